// Round 1
// baseline (236.270 us; speedup 1.0000x reference)
//
#include <hip/hip_runtime.h>
#include <math.h>

#define BB 131072
#define HH 64
#define NOB 32
#define NDIRS 8
#define LR_IT 1e-3f
#define TOLV 1e-3f
#define EPSV 1e-6f
#define NBLK 512
#define TPB 256

struct Ctrl { int flag; int parity; };

__device__ __forceinline__ void blockReduceToPartial(float v, float* partials) {
  __shared__ float lds[4];
  #pragma unroll
  for (int off = 32; off > 0; off >>= 1) v += __shfl_down(v, off, 64);
  int wid = threadIdx.x >> 6, lane = threadIdx.x & 63;
  if (lane == 0) lds[wid] = v;
  __syncthreads();
  if (threadIdx.x == 0) partials[blockIdx.x] = lds[0] + lds[1] + lds[2] + lds[3];
}

// ---- transpose small weight matrices into ws ----
__global__ __launch_bounds__(TPB) void prep_kernel(
    const float* __restrict__ Wr, const float* __restrict__ Win,
    const float* __restrict__ Wout,
    float* __restrict__ WrT, float* __restrict__ WoutT, float* __restrict__ WinT) {
  int t = threadIdx.x;
  for (int i = t; i < HH * HH; i += TPB) { int k = i >> 6, h = i & 63; WrT[i] = Wr[h * HH + k]; }
  for (int i = t; i < HH * NOB; i += TPB) { int h = i >> 5, o = i & 31; WoutT[i] = Wout[o * HH + h]; }
  for (int i = t; i < NDIRS * HH; i += TPB) { int d = i >> 6, h = i & 63; WinT[i] = Win[h * NDIRS + d]; }
}

// ---- init: prev = norm(x); s0 = norm(relu(prev@WrT + drive)); stored RAW with scales ----
__global__ __launch_bounds__(TPB) void init_kernel(
    const float* __restrict__ x, const int* __restrict__ dirs,
    const float* __restrict__ WrT, const float* __restrict__ WinT,
    float* __restrict__ bufA, float* __restrict__ bufS,
    float* __restrict__ scaleA, float* __restrict__ scaleS,
    float* __restrict__ partials) {
  int r = blockIdx.x * TPB + threadIdx.x;
  const float4* xr = (const float4*)(x + (size_t)r * HH);

  float ssx = 0.f, sx = 0.f;
  #pragma unroll
  for (int i = 0; i < 16; ++i) {
    float4 v = xr[i];
    ssx += v.x * v.x + v.y * v.y + v.z * v.z + v.w * v.w;
    sx += v.x + v.y + v.z + v.w;
  }
  float inv_x = 1.f / (sqrtf(ssx) + EPSV);

  float acc[HH];
  #pragma unroll
  for (int h = 0; h < HH; ++h) acc[h] = 0.f;
  #pragma unroll 1
  for (int k0 = 0; k0 < 16; ++k0) {
    float4 pv = xr[k0];
    const float* w0 = WrT + (k0 * 4 + 0) * HH;
    const float* w1 = WrT + (k0 * 4 + 1) * HH;
    const float* w2 = WrT + (k0 * 4 + 2) * HH;
    const float* w3 = WrT + (k0 * 4 + 3) * HH;
    #pragma unroll
    for (int h = 0; h < HH; ++h)
      acc[h] += pv.x * w0[h] + pv.y * w1[h] + pv.z * w2[h] + pv.w * w3[h];
  }

  int dir = dirs[r];
  const float4* wd = (const float4*)(WinT + dir * HH);
  float4* so = (float4*)(bufS + (size_t)r * HH);
  float ssg = 0.f, sg = 0.f;
  #pragma unroll
  for (int h0 = 0; h0 < 16; ++h0) {
    float4 d4 = wd[h0];
    float4 g;
    g.x = fmaxf(inv_x * acc[h0 * 4 + 0] + d4.x, 0.f);
    g.y = fmaxf(inv_x * acc[h0 * 4 + 1] + d4.y, 0.f);
    g.z = fmaxf(inv_x * acc[h0 * 4 + 2] + d4.z, 0.f);
    g.w = fmaxf(inv_x * acc[h0 * 4 + 3] + d4.w, 0.f);
    so[h0] = g;
    ssg += g.x * g.x + g.y * g.y + g.z * g.z + g.w * g.w;
    sg += g.x + g.y + g.z + g.w;
  }
  float inv_g = 1.f / (sqrtf(ssg) + EPSV);

  float4* ao = (float4*)(bufA + (size_t)r * HH);
  #pragma unroll
  for (int i = 0; i < 16; ++i) ao[i] = xr[i];
  scaleA[r] = inv_x;
  scaleS[r] = inv_g;

  float local = inv_x * sx - inv_g * sg;  // sum(prev - s) for this row
  blockReduceToPartial(local, partials);
}

#define PHASE_C_ONE(h, SCOMP, DCOMP)                       \
  {                                                        \
    float g = fmaxf(a_p * acc[h] + d4.DCOMP, 0.f);         \
    const float* wt = WoutT + (h) * NOB;                   \
    float w = 0.f;                                         \
    _Pragma("unroll")                                      \
    for (int o = 0; o < NOB; ++o) w += zz[o] * wt[o];      \
    float sv = a_s * s4.SCOMP;                             \
    float uu = sv + LR_IT * (g - sv + w);                  \
    u.DCOMP = uu;                                          \
    ssu += uu * uu;                                        \
    su += uu;                                              \
  }

// ---- one gated iteration ----
__global__ __launch_bounds__(TPB) void step_kernel(
    float* __restrict__ bufA, float* __restrict__ bufB,
    float* __restrict__ scaleA, float* __restrict__ scaleB,
    const float* __restrict__ WrT, const float* __restrict__ WoutT,
    const float* __restrict__ WinT,
    const int* __restrict__ dirs, const int* __restrict__ obs,
    float* __restrict__ partials, const Ctrl* __restrict__ ctrl) {
  if (ctrl->flag == 0) return;
  int p = ctrl->parity;
  float* S = p ? bufB : bufA;
  float* P = p ? bufA : bufB;
  float* sclS = p ? scaleB : scaleA;
  float* sclP = p ? scaleA : scaleB;

  int r = blockIdx.x * TPB + threadIdx.x;
  float a_s = sclS[r], a_p = sclP[r];
  const float4* sr = (const float4*)(S + (size_t)r * HH);

  // phase A: logits accumulators (raw scale; fold a_s later)
  float zz[NOB];
  #pragma unroll
  for (int o = 0; o < NOB; ++o) zz[o] = 0.f;
  float sS = 0.f;
  #pragma unroll 1
  for (int h0 = 0; h0 < 16; ++h0) {
    float4 s4 = sr[h0];
    sS += s4.x + s4.y + s4.z + s4.w;
    const float* wt0 = WoutT + (h0 * 4 + 0) * NOB;
    const float* wt1 = WoutT + (h0 * 4 + 1) * NOB;
    const float* wt2 = WoutT + (h0 * 4 + 2) * NOB;
    const float* wt3 = WoutT + (h0 * 4 + 3) * NOB;
    #pragma unroll
    for (int o = 0; o < NOB; ++o)
      zz[o] += s4.x * wt0[o] + s4.y * wt1[o] + s4.z * wt2[o] + s4.w * wt3[o];
  }

  // softmax on logits a_s*zz, then transform zz -> jp in place
  float m = -1e30f;
  #pragma unroll
  for (int o = 0; o < NOB; ++o) m = fmaxf(m, zz[o]);
  float se = 0.f;
  #pragma unroll
  for (int o = 0; o < NOB; ++o) { zz[o] = __expf(a_s * (zz[o] - m)); se += zz[o]; }
  float rse = 1.f / se;
  int ob = obs[r];
  float fob = 0.f, sf2 = 0.f;
  #pragma unroll
  for (int o = 0; o < NOB; ++o) {
    float f = zz[o] * rse;
    zz[o] = f;
    sf2 += f * f;
    fob += (o == ob) ? f : 0.f;
  }
  float fe = fob - sf2;
  #pragma unroll
  for (int o = 0; o < NOB; ++o) {
    float ep = ((o == ob) ? 1.f : 0.f) - zz[o];
    zz[o] = zz[o] * (ep - fe);  // jp
  }

  // phase B: acc = P_raw @ WrT  (g = relu(a_p*acc + drive))
  float acc[HH];
  #pragma unroll
  for (int h = 0; h < HH; ++h) acc[h] = 0.f;
  const float4* pr4 = (const float4*)(P + (size_t)r * HH);
  #pragma unroll 1
  for (int k0 = 0; k0 < 16; ++k0) {
    float4 pv = pr4[k0];
    const float* w0 = WrT + (k0 * 4 + 0) * HH;
    const float* w1 = WrT + (k0 * 4 + 1) * HH;
    const float* w2 = WrT + (k0 * 4 + 2) * HH;
    const float* w3 = WrT + (k0 * 4 + 3) * HH;
    #pragma unroll
    for (int h = 0; h < HH; ++h)
      acc[h] += pv.x * w0[h] + pv.y * w1[h] + pv.z * w2[h] + pv.w * w3[h];
  }

  int dir = dirs[r];
  const float4* wd = (const float4*)(WinT + dir * HH);

  // phase C: u = s + LR*(g - s + jp@Wout); write RAW u into P (becomes new s)
  float4* po = (float4*)(P + (size_t)r * HH);
  float ssu = 0.f, su = 0.f;
  #pragma unroll
  for (int h0 = 0; h0 < 16; ++h0) {
    float4 s4 = sr[h0];
    float4 d4 = wd[h0];
    float4 u;
    PHASE_C_ONE(h0 * 4 + 0, x, x)
    PHASE_C_ONE(h0 * 4 + 1, y, y)
    PHASE_C_ONE(h0 * 4 + 2, z, z)
    PHASE_C_ONE(h0 * 4 + 3, w, w)
    po[h0] = u;
  }
  float inv_u = 1.f / (sqrtf(ssu) + EPSV);
  sclP[r] = inv_u;

  float local = a_s * sS - inv_u * su;  // sum(prev_new - s_new) = sum(s_old) - sum(new_s)
  blockReduceToPartial(local, partials);
}

// ---- deterministic grid reduce + flag/parity update ----
__global__ __launch_bounds__(TPB) void reduce_kernel(
    const float* __restrict__ partials, Ctrl* ctrl, int first) {
  if (!first && ctrl->flag == 0) return;
  __shared__ float lds[4];
  float v = partials[threadIdx.x] + partials[threadIdx.x + 256];
  #pragma unroll
  for (int off = 32; off > 0; off >>= 1) v += __shfl_down(v, off, 64);
  int wid = threadIdx.x >> 6, lane = threadIdx.x & 63;
  if (lane == 0) lds[wid] = v;
  __syncthreads();
  if (threadIdx.x == 0) {
    float tot = lds[0] + lds[1] + lds[2] + lds[3];
    float mean = tot / (float)((size_t)BB * HH);
    int cond = (fabsf(mean) > TOLV) ? 1 : 0;
    if (first) { ctrl->parity = 1; ctrl->flag = cond; }
    else       { ctrl->parity ^= 1; ctrl->flag = cond; }
  }
}

// ---- final: preds = softmax(s@WoutT), write normalized s ----
__global__ __launch_bounds__(TPB) void final_kernel(
    const float* __restrict__ bufA, float* __restrict__ dout,
    const float* __restrict__ scaleA, const float* __restrict__ scaleB,
    const float* __restrict__ WoutT, const Ctrl* __restrict__ ctrl) {
  int p = ctrl->parity;
  const float* S = p ? (dout + (size_t)BB * NOB) : bufA;
  const float* scl = p ? scaleB : scaleA;
  int r = blockIdx.x * TPB + threadIdx.x;
  float a_s = scl[r];
  const float4* sr = (const float4*)(S + (size_t)r * HH);

  float zz[NOB];
  #pragma unroll
  for (int o = 0; o < NOB; ++o) zz[o] = 0.f;
  #pragma unroll 1
  for (int h0 = 0; h0 < 16; ++h0) {
    float4 s4 = sr[h0];
    const float* wt0 = WoutT + (h0 * 4 + 0) * NOB;
    const float* wt1 = WoutT + (h0 * 4 + 1) * NOB;
    const float* wt2 = WoutT + (h0 * 4 + 2) * NOB;
    const float* wt3 = WoutT + (h0 * 4 + 3) * NOB;
    #pragma unroll
    for (int o = 0; o < NOB; ++o)
      zz[o] += s4.x * wt0[o] + s4.y * wt1[o] + s4.z * wt2[o] + s4.w * wt3[o];
  }
  float m = -1e30f;
  #pragma unroll
  for (int o = 0; o < NOB; ++o) m = fmaxf(m, zz[o]);
  float se = 0.f;
  #pragma unroll
  for (int o = 0; o < NOB; ++o) { zz[o] = __expf(a_s * (zz[o] - m)); se += zz[o]; }
  float rse = 1.f / se;
  #pragma unroll
  for (int o = 0; o < NOB; ++o) zz[o] *= rse;

  // write preds
  float4* po = (float4*)(dout + (size_t)r * NOB);
  #pragma unroll
  for (int o4 = 0; o4 < 8; ++o4) {
    float4 f;
    f.x = zz[o4 * 4 + 0]; f.y = zz[o4 * 4 + 1];
    f.z = zz[o4 * 4 + 2]; f.w = zz[o4 * 4 + 3];
    po[o4] = f;
  }
  // write normalized s (in-place safe when p==1: read-then-write same addr per element)
  float4* so = (float4*)(dout + (size_t)BB * NOB + (size_t)r * HH);
  #pragma unroll
  for (int h0 = 0; h0 < 16; ++h0) {
    float4 s4 = sr[h0];
    s4.x *= a_s; s4.y *= a_s; s4.z *= a_s; s4.w *= a_s;
    so[h0] = s4;
  }
}

extern "C" void kernel_launch(void* const* d_in, const int* in_sizes, int n_in,
                              void* d_out, int out_size, void* d_ws, size_t ws_size,
                              hipStream_t stream) {
  const int* dirs = (const int*)d_in[0];
  const int* obs = (const int*)d_in[1];
  const float* x = (const float*)d_in[2];
  const float* Wr = (const float*)d_in[3];
  const float* Win = (const float*)d_in[4];
  const float* Wout = (const float*)d_in[5];
  float* out = (float*)d_out;
  float* ws = (float*)d_ws;

  float* bufA = ws;                            // B*H raw state
  float* scaleA = ws + (size_t)BB * HH;        // B
  float* scaleB = scaleA + BB;                 // B
  float* partials = scaleB + BB;               // NBLK
  float* WrT = partials + NBLK;                // 64*64
  float* WoutT = WrT + HH * HH;                // 64*32
  float* WinT = WoutT + HH * NOB;              // 8*64
  Ctrl* ctrl = (Ctrl*)(WinT + NDIRS * HH);
  float* bufB = out + (size_t)BB * NOB;        // s slice of d_out used as raw state

  prep_kernel<<<1, TPB, 0, stream>>>(Wr, Win, Wout, WrT, WoutT, WinT);
  init_kernel<<<NBLK, TPB, 0, stream>>>(x, dirs, WrT, WinT, bufA, bufB, scaleA, scaleB, partials);
  reduce_kernel<<<1, TPB, 0, stream>>>(partials, ctrl, 1);
  for (int k = 0; k < 10; ++k) {
    step_kernel<<<NBLK, TPB, 0, stream>>>(bufA, bufB, scaleA, scaleB, WrT, WoutT, WinT,
                                          dirs, obs, partials, ctrl);
    reduce_kernel<<<1, TPB, 0, stream>>>(partials, ctrl, 0);
  }
  final_kernel<<<NBLK, TPB, 0, stream>>>(bufA, out, scaleA, scaleB, WoutT, ctrl);
}